// Round 10
// baseline (265.219 us; speedup 1.0000x reference)
//
#include <hip/hip_runtime.h>
#include <math.h>

#define HH 256
#define WW 256
static constexpr int HW = HH * WW;
static constexpr float MIN_D = 0.1f;
static constexpr float MAX_D = 10.0f;
static constexpr float C1c = 1e-4f;   // 0.01^2
static constexpr float C2c = 9e-4f;   // 0.03^2
static constexpr float ZW_SCALE = 1048576.f;   // 2^20
static constexpr float W_SCALE  = 4194304.f;   // 2^22

__device__ inline unsigned shdu(unsigned v, int o) {
    return (unsigned)__shfl_down((int)v, o, 64);
}
__device__ inline float shdf(float v, int o) {
    return __shfl_down(v, o, 64);
}

// Software grid barrier: valid because grid <= occupancy-derived co-residency.
// bar[0]=arrival counter, bar[1]=generation. Releaser resets bar[0] BEFORE
// bumping gen, so the barrier is immediately reusable and replay-safe.
__device__ inline void grid_barrier(unsigned* __restrict__ bar, int nblk) {
    __syncthreads();
    if (threadIdx.x == 0) {
        __threadfence();   // prior writes device-visible before arrival
        unsigned g = __hip_atomic_load(&bar[1], __ATOMIC_RELAXED, __HIP_MEMORY_SCOPE_AGENT);
        unsigned old = __hip_atomic_fetch_add(&bar[0], 1u, __ATOMIC_ACQ_REL, __HIP_MEMORY_SCOPE_AGENT);
        if (old == (unsigned)(nblk - 1)) {
            __hip_atomic_store(&bar[0], 0u, __ATOMIC_RELAXED, __HIP_MEMORY_SCOPE_AGENT);
            __hip_atomic_store(&bar[1], g + 1u, __ATOMIC_RELEASE, __HIP_MEMORY_SCOPE_AGENT);
        } else {
            while (__hip_atomic_load(&bar[1], __ATOMIC_ACQUIRE, __HIP_MEMORY_SCOPE_AGENT) == g)
                __builtin_amdgcn_s_sleep(2);
        }
    }
    __syncthreads();
}

// Zero the 2-word barrier state (d_ws may be re-poisoned between replays).
__global__ void init_k(unsigned* __restrict__ bar) {
    if (threadIdx.x < 2) bar[threadIdx.x] = 0u;
}

// ---------------------------------------------------------------------------
// Single kernel: init -> scatter -> finalize/minmax -> ssim+out, separated by
// software grid barriers. One dispatch = one kernel-boundary maintenance pass
// over the atomic-dirtied acc region. Cross-phase data uses agent-scope
// atomics (coherence point), immune to non-coherent XCD L2s.
// ---------------------------------------------------------------------------
__global__ __launch_bounds__(256) void mono_k(
        const float* __restrict__ pts, const float* __restrict__ dens,
        const float* __restrict__ gt, unsigned long long* __restrict__ acc,
        float* __restrict__ raw, unsigned* __restrict__ mm,
        float* __restrict__ accum, unsigned* __restrict__ ticket,
        unsigned* __restrict__ bar, float* __restrict__ out,
        int N, int total, int nblk) {
    __shared__ float hs[5][266];
    __shared__ float sb[3][4];
    __shared__ unsigned sm[4][4];

    const int tid  = threadIdx.x;
    const int gtid = blockIdx.x * 256 + tid;
    const int GSZ  = gridDim.x * 256;
    const int B    = total / N;
    const int BHW  = B * HW;

    // ---- P0: init acc (agent-scope stores, visible to far atomics) ----
    for (int i = gtid; i < BHW; i += GSZ)
        __hip_atomic_store(&acc[i], 0ull, __ATOMIC_RELAXED, __HIP_MEMORY_SCOPE_AGENT);
    if (gtid < 8)        __hip_atomic_store(&mm[gtid], 0xFFFFFFFFu, __ATOMIC_RELAXED, __HIP_MEMORY_SCOPE_AGENT);
    else if (gtid < 16)  __hip_atomic_store(&mm[gtid], 0u, __ATOMIC_RELAXED, __HIP_MEMORY_SCOPE_AGENT);
    else if (gtid < 19)  __hip_atomic_store(&accum[gtid - 16], 0.f, __ATOMIC_RELAXED, __HIP_MEMORY_SCOPE_AGENT);
    else if (gtid == 19) __hip_atomic_store(ticket, 0u, __ATOMIC_RELAXED, __HIP_MEMORY_SCOPE_AGENT);
    grid_barrier(bar, nblk);

    // ---- P1: scatter (4 consecutive pts/iter via 3+1 dwordx4 loads) ----
    {
        const float4* p4 = (const float4*)pts;
        const float4* d4 = (const float4*)dens;
        int total4 = total >> 2;
        int N2 = N << 1, N3 = N * 3;
        for (int g = gtid; g < total4; g += GSZ) {
            float4 A = p4[3 * g], Bv = p4[3 * g + 1], C = p4[3 * g + 2];
            float4 D = d4[g];
            float xs[4] = {A.x, A.w, Bv.z, C.y};
            float ys[4] = {A.y, Bv.x, Bv.w, C.z};
            float zs[4] = {A.z, Bv.y, C.x, C.w};
            float ds[4] = {D.x, D.y, D.z, D.w};
            int p0 = g << 2;
            int b = (p0 >= N) + (p0 >= N2) + (p0 >= N3);   // N%4==0: same batch
            unsigned long long* accb = acc + (size_t)b * HW;
#pragma unroll
            for (int j = 0; j < 4; ++j) {
                float z = zs[j];
                if (!(z > MIN_D)) continue;             // strict z > MIN_DEPTH
                float invz = __builtin_amdgcn_rcpf(z);
                invz = invz * (2.0f - z * invz);        // Newton -> ~1 ulp
                float u = (xs[j] * invz + 0.5f) * (float)WW;
                float v = (ys[j] * invz + 0.5f) * (float)HH;
                if (!(u >= 0.f && u < (float)WW && v >= 0.f && v < (float)HH)) continue;
                int ui = (int)u;                        // trunc == floor (u>=0)
                int vi = (int)v;
                float w = __builtin_amdgcn_rcpf(1.f + __expf(-ds[j]));  // sigmoid
                unsigned hi = (unsigned)__float2int_rn(z * w * ZW_SCALE);
                unsigned lo = (unsigned)__float2int_rn(w * W_SCALE);
                atomicAdd(&accb[(vi << 8) | ui],
                          ((unsigned long long)hi << 32) | lo);
            }
        }
    }
    grid_barrier(bar, nblk);

    // ---- P2: depth=(hi/lo)*4 -> raw (agent store); per-batch minmax ----
    {
        unsigned dmin[4] = {0xFFFFFFFFu, 0xFFFFFFFFu, 0xFFFFFFFFu, 0xFFFFFFFFu};
        unsigned dmax[4] = {0, 0, 0, 0};
        unsigned gmn[4]  = {0xFFFFFFFFu, 0xFFFFFFFFu, 0xFFFFFFFFu, 0xFFFFFFFFu};
        unsigned gmx[4]  = {0, 0, 0, 0};
        for (int i = gtid; i < BHW; i += GSZ) {
            int b = i >> 16;                        // i / HW
            unsigned long long v = __hip_atomic_load(&acc[i], __ATOMIC_RELAXED,
                                                     __HIP_MEMORY_SCOPE_AGENT);
            unsigned lo = (unsigned)v;
            unsigned hi = (unsigned)(v >> 32);
            float d = lo ? ((float)hi / (float)lo) * 4.0f : 0.f;
            __hip_atomic_store(&raw[i], d, __ATOMIC_RELAXED, __HIP_MEMORY_SCOPE_AGENT);
            float g = gt[i];
            if (d > 0.f) {
                unsigned du = __float_as_uint(d);
                dmin[b] = min(dmin[b], du); dmax[b] = max(dmax[b], du);
            }
            if (g > 0.f) {
                unsigned gu = __float_as_uint(g);
                gmn[b] = min(gmn[b], gu); gmx[b] = max(gmx[b], gu);
            }
        }
#pragma unroll
        for (int b = 0; b < 4; ++b) {
            unsigned a0 = dmin[b], a1 = gmn[b], a2 = dmax[b], a3 = gmx[b];
            for (int o = 32; o; o >>= 1) {
                a0 = min(a0, shdu(a0, o)); a1 = min(a1, shdu(a1, o));
                a2 = max(a2, shdu(a2, o)); a3 = max(a3, shdu(a3, o));
            }
            int wid = tid >> 6, lane = tid & 63;
            if (lane == 0) { sm[0][wid] = a0; sm[1][wid] = a1; sm[2][wid] = a2; sm[3][wid] = a3; }
            __syncthreads();
            if (tid == 0) {
                unsigned m0 = min(min(sm[0][0], sm[0][1]), min(sm[0][2], sm[0][3]));
                unsigned m1 = min(min(sm[1][0], sm[1][1]), min(sm[1][2], sm[1][3]));
                unsigned m2 = max(max(sm[2][0], sm[2][1]), max(sm[2][2], sm[2][3]));
                unsigned m3 = max(max(sm[3][0], sm[3][1]), max(sm[3][2], sm[3][3]));
                if (m0 != 0xFFFFFFFFu) atomicMin(&mm[b], m0);
                if (m1 != 0xFFFFFFFFu) atomicMin(&mm[4 + b], m1);
                if (m2) atomicMax(&mm[8 + b], m2);
                if (m3) atomicMax(&mm[12 + b], m3);
            }
            __syncthreads();
        }
    }
    grid_barrier(bar, nblk);

    // ---- P3: normalize + separable 11x11 SSIM + masked L1 + combine ----
    const int nb = B * 64;                         // 64 row-bands per batch
    for (int band = blockIdx.x; band < nb; band += gridDim.x) {
        int z  = band >> 6;
        int r0 = (band & 63) * 4;
        int tx = tid;
        const float* P = raw + (size_t)z * HW;
        const float* T = gt + (size_t)z * HW;

        unsigned mmz0 = __hip_atomic_load(&mm[z],      __ATOMIC_RELAXED, __HIP_MEMORY_SCOPE_AGENT);
        unsigned mmz1 = __hip_atomic_load(&mm[4 + z],  __ATOMIC_RELAXED, __HIP_MEMORY_SCOPE_AGENT);
        unsigned mmz2 = __hip_atomic_load(&mm[8 + z],  __ATOMIC_RELAXED, __HIP_MEMORY_SCOPE_AGENT);
        unsigned mmz3 = __hip_atomic_load(&mm[12 + z], __ATOMIC_RELAXED, __HIP_MEMORY_SCOPE_AGENT);
        bool hasP = mmz2 != 0u;
        float pmin_m = hasP ? fmaxf(__uint_as_float(mmz0), MIN_D) : 0.f;
        float pscale = 1.f / ((hasP ? fminf(__uint_as_float(mmz2), MAX_D) : MAX_D) - pmin_m + 1e-8f);
        bool hasG = mmz3 != 0u;
        float gmin_m = hasG ? fmaxf(__uint_as_float(mmz1), MIN_D) : 0.f;
        float gscale = 1.f / ((hasG ? fminf(__uint_as_float(mmz3), MAX_D) : MAX_D) - gmin_m + 1e-8f);

        float p[14], t[14];
#pragma unroll
        for (int i = 0; i < 14; ++i) {
            int row = r0 - 5 + i;
            bool ok = (row >= 0) && (row < HH);
            float dv = ok ? __hip_atomic_load(&P[row * WW + tx], __ATOMIC_RELAXED,
                                              __HIP_MEMORY_SCOPE_AGENT) : 0.f;
            float gv = ok ? T[row * WW + tx] : 0.f;
            p[i] = (dv - pmin_m) * pscale * (dv > 0.f ? 1.f : 0.f);
            t[i] = (gv - gmin_m) * gscale * (gv > 0.f ? 1.f : 0.f);
        }
        if (tx < 5) {
#pragma unroll
            for (int q = 0; q < 5; ++q) { hs[q][tx] = 0.f; hs[q][261 + tx] = 0.f; }
        }
        __syncthreads();

        const float inv121 = 1.f / 121.f;
        float svA = 0.f, mA = 0.f, lvA = 0.f;
#pragma unroll
        for (int r = 0; r < 4; ++r) {
            float s1 = 0, s2 = 0, s11 = 0, s22 = 0, s12 = 0;
#pragma unroll
            for (int k = 0; k < 11; ++k) {
                float pp = p[r + k], tt = t[r + k];
                s1 += pp; s2 += tt;
                s11 = fmaf(pp, pp, s11); s22 = fmaf(tt, tt, s22); s12 = fmaf(pp, tt, s12);
            }
            hs[0][5 + tx] = s1; hs[1][5 + tx] = s2; hs[2][5 + tx] = s11;
            hs[3][5 + tx] = s22; hs[4][5 + tx] = s12;
            __syncthreads();
            float h1 = 0, h2 = 0, h11 = 0, h22 = 0, h12 = 0;
#pragma unroll
            for (int k = 0; k < 11; ++k) {
                h1 += hs[0][tx + k]; h2 += hs[1][tx + k]; h11 += hs[2][tx + k];
                h22 += hs[3][tx + k]; h12 += hs[4][tx + k];
            }
            float mu1 = h1 * inv121, mu2 = h2 * inv121;
            float mu1sq = mu1 * mu1, mu2sq = mu2 * mu2, mu12 = mu1 * mu2;
            float sig1 = h11 * inv121 - mu1sq;
            float sig2 = h22 * inv121 - mu2sq;
            float sig12 = h12 * inv121 - mu12;
            float smap = (2.f * mu12 + C1c) * (2.f * sig12 + C2c) /
                         ((mu1sq + mu2sq + C1c) * (sig1 + sig2 + C2c));
            float pc = p[r + 5], tc = t[r + 5];
            float m = (pc > 0.f && tc > 0.f) ? 1.f : 0.f;
            svA += smap * m;
            mA  += m;
            lvA += m * fabsf(pc - tc);
            __syncthreads();
        }

        for (int o = 32; o; o >>= 1) {
            svA += shdf(svA, o); mA += shdf(mA, o); lvA += shdf(lvA, o);
        }
        int wid = tx >> 6, lane = tx & 63;
        if (lane == 0) { sb[0][wid] = svA; sb[1][wid] = mA; sb[2][wid] = lvA; }
        __syncthreads();
        if (tx == 0) {
            unsafeAtomicAdd(&accum[0], sb[0][0] + sb[0][1] + sb[0][2] + sb[0][3]);
            unsafeAtomicAdd(&accum[1], sb[1][0] + sb[1][1] + sb[1][2] + sb[1][3]);
            unsafeAtomicAdd(&accum[2], sb[2][0] + sb[2][1] + sb[2][2] + sb[2][3]);
            __threadfence();                       // drain our adds
            unsigned old = atomicAdd(ticket, 1u);
            if (old == (unsigned)(nb - 1)) {       // last band: all adds visible
                __threadfence();
                float ss = __hip_atomic_load(&accum[0], __ATOMIC_RELAXED, __HIP_MEMORY_SCOPE_AGENT);
                float ms = __hip_atomic_load(&accum[1], __ATOMIC_RELAXED, __HIP_MEMORY_SCOPE_AGENT);
                float ls = __hip_atomic_load(&accum[2], __ATOMIC_RELAXED, __HIP_MEMORY_SCOPE_AGENT);
                float l1   = ls / (ms + 1e-8f);
                float ssim = 1.f - ss / (ms + 1e-8f);
                float total_l = fminf(0.8f * l1 + 0.2f * ssim, 1.0f);
                out[0] = (ms < 10.f) ? 0.f : total_l;
            }
        }
        __syncthreads();   // protect hs/sb reuse across band iterations
    }
}

extern "C" void kernel_launch(void* const* d_in, const int* in_sizes, int n_in,
                              void* d_out, int out_size, void* d_ws, size_t ws_size,
                              hipStream_t stream) {
    const float* pts = (const float*)d_in[0];
    const float* dens = (const float*)d_in[1];
    const float* gt = (const float*)d_in[2];
    int B = in_sizes[2] / HW;      // 4
    int N = in_sizes[1] / B;       // 2,000,000
    int total = B * N;             // 8,000,000
    int BHW = B * HW;

    unsigned long long* acc = (unsigned long long*)d_ws;      // [B*HW] u64
    float* raw  = (float*)(acc + (size_t)BHW);                // [B*HW] f32
    unsigned* mm = (unsigned*)(raw + (size_t)BHW);            // 16 u32
    float* accum = (float*)(mm + 16);                         // 3 f32
    unsigned* ticket = (unsigned*)(accum + 3);                // 1 u32
    unsigned* bar = (unsigned*)(((char*)(ticket + 1)) + 108); // own cache line
    float* outp = (float*)d_out;

    // Co-residency-safe grid: occupancy query for THIS kernel (deterministic,
    // host-side, graph-capture-safe). Floor at 256 (1 block/CU is always
    // co-resident for a 256-thread / 5.5KB-LDS kernel), cap at 1024.
    int maxb = 0;
    (void)hipOccupancyMaxActiveBlocksPerMultiprocessor(&maxb, (const void*)mono_k, 256, 0);
    int ncu = 0;
    (void)hipDeviceGetAttribute(&ncu, hipDeviceAttributeMultiprocessorCount, 0);
    if (maxb < 1) maxb = 1;
    if (ncu < 1) ncu = 256;
    long long grid_ll = (long long)maxb * ncu;
    int grid = (int)(grid_ll < 256 ? 256 : (grid_ll > 1024 ? 1024 : grid_ll));

    init_k<<<1, 64, 0, stream>>>(bar);
    mono_k<<<grid, 256, 0, stream>>>(pts, dens, gt, acc, raw, mm, accum, ticket,
                                     bar, outp, N, total, grid);
}

// Round 11
// 107.818 us; speedup vs baseline: 2.4599x; 2.4599x over previous
//
#include <hip/hip_runtime.h>
#include <math.h>

#define HH 256
#define WW 256
static constexpr int HW = HH * WW;
static constexpr float MIN_D = 0.1f;
static constexpr float MAX_D = 10.0f;
static constexpr float C1c = 1e-4f;   // 0.01^2
static constexpr float C2c = 9e-4f;   // 0.03^2
static constexpr float ZW_SCALE = 1048576.f;   // 2^20
static constexpr float W_SCALE  = 4194304.f;   // 2^22

__device__ inline unsigned shdu(unsigned v, int o) {
    return (unsigned)__shfl_down((int)v, o, 64);
}

// ---------------------------------------------------------------------------
// Stage 0: zero the u64 accumulator (16B stores) + init mm/accum/ticket.
// (2MB via 512 blocks; replaces rocclr fillBufferAligned which ran at 38GB/s.)
// ---------------------------------------------------------------------------
__global__ __launch_bounds__(256) void zero_k(ulonglong2* __restrict__ accv,
                          unsigned* __restrict__ mm, float* __restrict__ accum,
                          unsigned* __restrict__ ticket, int n16) {
    int i = blockIdx.x * 256 + threadIdx.x;
    if (i < n16) accv[i] = ulonglong2{0ull, 0ull};
    if (blockIdx.x == 0) {
        int tt = threadIdx.x;
        if (tt < 8) mm[tt] = 0xFFFFFFFFu;                 // minP, minG slots
        else if (tt < 16) mm[tt] = 0u;                    // maxP, maxG slots
        else if (tt < 19) accum[tt - 16] = 0.f;           // ssim/mask/l1 sums
        else if (tt == 19) *ticket = 0u;
    }
}

// ---------------------------------------------------------------------------
// Stage 1: weighted z-buffer scatter — R3's fastest-measured variant (~30us
// in-graph): 8 points/thread, 6x float4 pts loads + 2x float4 dens loads,
// one u64 fixed-point atomic per valid point (hi=zw*2^20, lo=w*2^22).
// Per-pixel sums bounded (~50, ~15) << field capacities (2048, 1024): no carry.
// ---------------------------------------------------------------------------
__global__ __launch_bounds__(256) void scatter_k(const float4* __restrict__ pts4,
                          const float4* __restrict__ dens4,
                          unsigned long long* __restrict__ acc,
                          int nthreads, int N) {
    int t = blockIdx.x * 256 + threadIdx.x;
    if (t >= nthreads) return;
    float4 P0 = pts4[6 * t], P1 = pts4[6 * t + 1], P2 = pts4[6 * t + 2];
    float4 P3 = pts4[6 * t + 3], P4 = pts4[6 * t + 4], P5 = pts4[6 * t + 5];
    float4 D0 = dens4[2 * t], D1 = dens4[2 * t + 1];
    float xs[8] = {P0.x, P0.w, P1.z, P2.y, P3.x, P3.w, P4.z, P5.y};
    float ys[8] = {P0.y, P1.x, P1.w, P2.z, P3.y, P4.x, P4.w, P5.z};
    float zs[8] = {P0.z, P1.y, P2.x, P2.w, P3.z, P4.y, P5.x, P5.w};
    float ds[8] = {D0.x, D0.y, D0.z, D0.w, D1.x, D1.y, D1.z, D1.w};
    int base = 8 * t;
    int b = base / N;              // N % 8 == 0 -> all 8 points share a batch
    unsigned long long* accb = acc + (size_t)b * HW;
#pragma unroll
    for (int k = 0; k < 8; ++k) {
        float z = zs[k];
        if (!(z > MIN_D)) continue;                 // strict z > MIN_DEPTH
        float u = (xs[k] / z + 0.5f) * (float)WW;   // IEEE div: exact binning
        float v = (ys[k] / z + 0.5f) * (float)HH;
        if (!(u >= 0.f && u < (float)WW && v >= 0.f && v < (float)HH)) continue;
        int ui = (int)u;                            // trunc == floor (u >= 0)
        int vi = (int)v;
        float w = __builtin_amdgcn_rcpf(1.f + __expf(-ds[k]));  // sigmoid
        unsigned hi = (unsigned)__float2int_rn(z * w * ZW_SCALE);
        unsigned lo = (unsigned)__float2int_rn(w * W_SCALE);
        unsigned long long pk = ((unsigned long long)hi << 32) | lo;
        atomicAdd(&accb[(vi << 8) | ui], pk);
    }
}

// ---------------------------------------------------------------------------
// Stage 2: depth = (hi/lo)*4 (where lo>0) -> raw; per-batch min/max of valid
// pred & gt via uint-bit atomics.
// mm layout: [0..3]=minP, [4..7]=minG, [8..11]=maxP, [12..15]=maxG
// ---------------------------------------------------------------------------
__global__ __launch_bounds__(256) void finalize_k(const unsigned long long* __restrict__ acc,
                           const float* __restrict__ gt, float* __restrict__ raw,
                           unsigned* __restrict__ mm) {
    int i = blockIdx.x * 256 + threadIdx.x;
    int b = blockIdx.x >> 8;
    unsigned long long v = acc[i];
    unsigned lo = (unsigned)v;
    unsigned hi = (unsigned)(v >> 32);
    float d = lo ? ((float)hi / (float)lo) * 4.0f : 0.f;   // (hi/2^20)/(lo/2^22)
    raw[i] = d;
    float g = gt[i];
    unsigned dmin = d > 0.f ? __float_as_uint(d) : 0xFFFFFFFFu;
    unsigned dmax = d > 0.f ? __float_as_uint(d) : 0u;
    unsigned gmin = g > 0.f ? __float_as_uint(g) : 0xFFFFFFFFu;
    unsigned gmax = g > 0.f ? __float_as_uint(g) : 0u;
    for (int o = 32; o; o >>= 1) {
        dmin = min(dmin, shdu(dmin, o));
        gmin = min(gmin, shdu(gmin, o));
        dmax = max(dmax, shdu(dmax, o));
        gmax = max(gmax, shdu(gmax, o));
    }
    __shared__ unsigned sm[4][4];
    int wid = threadIdx.x >> 6, lane = threadIdx.x & 63;
    if (lane == 0) { sm[0][wid] = dmin; sm[1][wid] = gmin; sm[2][wid] = dmax; sm[3][wid] = gmax; }
    __syncthreads();
    if (threadIdx.x == 0) {
        unsigned m0 = min(min(sm[0][0], sm[0][1]), min(sm[0][2], sm[0][3]));
        unsigned m1 = min(min(sm[1][0], sm[1][1]), min(sm[1][2], sm[1][3]));
        unsigned m2 = max(max(sm[2][0], sm[2][1]), max(sm[2][2], sm[2][3]));
        unsigned m3 = max(max(sm[3][0], sm[3][1]), max(sm[3][2], sm[3][3]));
        atomicMin(&mm[b], m0);
        atomicMin(&mm[4 + b], m1);
        atomicMax(&mm[8 + b], m2);
        atomicMax(&mm[12 + b], m3);
    }
}

// ---------------------------------------------------------------------------
// Stage 3: fused normalize + separable 11x11 zero-padded box SSIM + masked L1
// + final combine (last block via atomic ticket). Row-band structure:
// block = 256 threads = one column each; 4 output rows per block; 14 guarded
// coalesced row loads into registers; vertical sums in regs; horizontal sums
// via 266-wide zero-padded LDS rows (stride-1, conflict-free).
// accum[0]=ssim_sum, accum[1]=mask_sum, accum[2]=l1_sum
// ---------------------------------------------------------------------------
__global__ __launch_bounds__(256) void ssim_k(const float* __restrict__ raw,
                       const float* __restrict__ gt, const unsigned* __restrict__ mm,
                       float* __restrict__ accum, unsigned* __restrict__ ticket,
                       float* __restrict__ out, int nblocks) {
    __shared__ float hs[5][266];
    __shared__ float sb[3][4];
    int z = blockIdx.y;
    int r0 = blockIdx.x * 4;
    int tx = threadIdx.x;
    const float* P = raw + (size_t)z * HW;
    const float* T = gt + (size_t)z * HW;

    bool hasP = mm[8 + z] != 0u;
    float pmin_m = hasP ? fmaxf(__uint_as_float(mm[z]), MIN_D) : 0.f;
    float pscale = 1.f / ((hasP ? fminf(__uint_as_float(mm[8 + z]), MAX_D) : MAX_D) - pmin_m + 1e-8f);
    bool hasG = mm[12 + z] != 0u;
    float gmin_m = hasG ? fmaxf(__uint_as_float(mm[4 + z]), MIN_D) : 0.f;
    float gscale = 1.f / ((hasG ? fminf(__uint_as_float(mm[12 + z]), MAX_D) : MAX_D) - gmin_m + 1e-8f);

    // 14 rows (r0-5 .. r0+8), normalized; out-of-image rows -> 0 (zero-pad)
    float p[14], t[14];
#pragma unroll
    for (int i = 0; i < 14; ++i) {
        int row = r0 - 5 + i;
        bool ok = (row >= 0) && (row < HH);
        float dv = ok ? P[row * WW + tx] : 0.f;
        float gv = ok ? T[row * WW + tx] : 0.f;
        p[i] = (dv - pmin_m) * pscale * (dv > 0.f ? 1.f : 0.f);
        t[i] = (gv - gmin_m) * gscale * (gv > 0.f ? 1.f : 0.f);
    }
    if (tx < 5) {
#pragma unroll
        for (int q = 0; q < 5; ++q) { hs[q][tx] = 0.f; hs[q][261 + tx] = 0.f; }
    }
    __syncthreads();

    const float inv121 = 1.f / 121.f;
    float svA = 0.f, mA = 0.f, lvA = 0.f;
#pragma unroll
    for (int r = 0; r < 4; ++r) {
        float s1 = 0, s2 = 0, s11 = 0, s22 = 0, s12 = 0;
#pragma unroll
        for (int k = 0; k < 11; ++k) {
            float pp = p[r + k], tt = t[r + k];
            s1 += pp; s2 += tt;
            s11 = fmaf(pp, pp, s11); s22 = fmaf(tt, tt, s22); s12 = fmaf(pp, tt, s12);
        }
        hs[0][5 + tx] = s1; hs[1][5 + tx] = s2; hs[2][5 + tx] = s11;
        hs[3][5 + tx] = s22; hs[4][5 + tx] = s12;
        __syncthreads();
        float h1 = 0, h2 = 0, h11 = 0, h22 = 0, h12 = 0;
#pragma unroll
        for (int k = 0; k < 11; ++k) {
            h1 += hs[0][tx + k]; h2 += hs[1][tx + k]; h11 += hs[2][tx + k];
            h22 += hs[3][tx + k]; h12 += hs[4][tx + k];
        }
        float mu1 = h1 * inv121, mu2 = h2 * inv121;
        float mu1sq = mu1 * mu1, mu2sq = mu2 * mu2, mu12 = mu1 * mu2;
        float sig1 = h11 * inv121 - mu1sq;
        float sig2 = h22 * inv121 - mu2sq;
        float sig12 = h12 * inv121 - mu12;
        float smap = (2.f * mu12 + C1c) * (2.f * sig12 + C2c) /
                     ((mu1sq + mu2sq + C1c) * (sig1 + sig2 + C2c));
        float pc = p[r + 5], tc = t[r + 5];
        float m = (pc > 0.f && tc > 0.f) ? 1.f : 0.f;
        svA += smap * m;
        mA  += m;
        lvA += m * fabsf(pc - tc);
        __syncthreads();
    }

    for (int o = 32; o; o >>= 1) {
        svA += __shfl_down(svA, o, 64);
        mA  += __shfl_down(mA, o, 64);
        lvA += __shfl_down(lvA, o, 64);
    }
    int wid = tx >> 6, lane = tx & 63;
    if (lane == 0) { sb[0][wid] = svA; sb[1][wid] = mA; sb[2][wid] = lvA; }
    __syncthreads();
    if (tx == 0) {
        unsafeAtomicAdd(&accum[0], sb[0][0] + sb[0][1] + sb[0][2] + sb[0][3]);
        unsafeAtomicAdd(&accum[1], sb[1][0] + sb[1][1] + sb[1][2] + sb[1][3]);
        unsafeAtomicAdd(&accum[2], sb[2][0] + sb[2][1] + sb[2][2] + sb[2][3]);
        __threadfence();                       // drain our adds
        unsigned old = atomicAdd(ticket, 1u);
        if (old == (unsigned)(nblocks - 1)) {  // last block: all adds visible
            __threadfence();
            float ss = __hip_atomic_load(&accum[0], __ATOMIC_RELAXED, __HIP_MEMORY_SCOPE_AGENT);
            float ms = __hip_atomic_load(&accum[1], __ATOMIC_RELAXED, __HIP_MEMORY_SCOPE_AGENT);
            float ls = __hip_atomic_load(&accum[2], __ATOMIC_RELAXED, __HIP_MEMORY_SCOPE_AGENT);
            float l1   = ls / (ms + 1e-8f);
            float ssim = 1.f - ss / (ms + 1e-8f);
            float total = fminf(0.8f * l1 + 0.2f * ssim, 1.0f);
            out[0] = (ms < 10.f) ? 0.f : total;
        }
    }
}

extern "C" void kernel_launch(void* const* d_in, const int* in_sizes, int n_in,
                              void* d_out, int out_size, void* d_ws, size_t ws_size,
                              hipStream_t stream) {
    const float* pts = (const float*)d_in[0];
    const float* dens = (const float*)d_in[1];
    const float* gt = (const float*)d_in[2];
    int B = in_sizes[2] / HW;      // 4
    int N = in_sizes[1] / B;       // 2,000,000
    int total = B * N;             // 8,000,000
    int BHW = B * HW;

    unsigned long long* acc = (unsigned long long*)d_ws;      // [B*HW] u64
    float* raw  = (float*)(acc + (size_t)BHW);                // [B*HW] f32
    unsigned* mm = (unsigned*)(raw + (size_t)BHW);            // 16 u32
    float* accum = (float*)(mm + 16);                         // 3 f32
    unsigned* ticket = (unsigned*)(accum + 3);                // 1 u32

    int n16 = BHW / 2;                         // ulonglong2 count (2MB)
    zero_k<<<(n16 + 255) / 256, 256, 0, stream>>>((ulonglong2*)acc, mm, accum,
                                                  ticket, n16);

    int nthreads = total / 8;                  // 8 consecutive points / thread
    scatter_k<<<(nthreads + 255) / 256, 256, 0, stream>>>((const float4*)pts,
                                                          (const float4*)dens,
                                                          acc, nthreads, N);
    finalize_k<<<B * 256, 256, 0, stream>>>(acc, gt, raw, mm);
    int nblocks = 64 * B;
    ssim_k<<<dim3(64, B), 256, 0, stream>>>(raw, gt, mm, accum, ticket,
                                            (float*)d_out, nblocks);
}